// Round 1
// baseline (986.022 us; speedup 1.0000x reference)
//
#include <hip/hip_runtime.h>

// Problem constants (fixed by the reference).
#define N_VAR 16
#define LAGS  16
#define HID   16
#define GRP   256        // N_VAR * N_VAR
#define BATCH 32768

// fast sigmoid: rcp(1 + exp(-t)); v_exp_f32 + v_rcp_f32, ~1 ulp each — far
// inside the 1.2e-2 absmax threshold.
__device__ __forceinline__ float sigmoid_fast(float t) {
    float e = __expf(-t);                       // v_mul + v_exp_f32
    return __builtin_amdgcn_rcpf(1.0f + e);     // v_add + v_rcp_f32
}

// One wave = one variable v (wave-uniform) x 64 consecutive batch rows.
// Loop over n (the 16 groups g = v*16+n feeding variable v). Weights are
// wave-uniform -> compiler emits s_load / SGPR operands; no LDS needed.
__global__ __launch_bounds__(256) void additive_model_kernel(
    const float* __restrict__ x,       // [B, G, L]
    const int*   __restrict__ causal,  // [G, L]  (reshaped N,N,L)
    const float* __restrict__ W1,      // [G, H, L]
    const float* __restrict__ b1,      // [G, H]
    const float* __restrict__ W2,      // [G, H, H]  (out k, in h)
    const float* __restrict__ b2,      // [G, H]
    const float* __restrict__ W3,      // [N, N*H]
    const float* __restrict__ b3,      // [N]
    float* __restrict__ out)           // [B, N]
{
    const int gid  = blockIdx.x * blockDim.x + threadIdx.x;
    const int wave = gid >> 6;
    const int lane = gid & 63;

    int v = wave & (N_VAR - 1);
    v = __builtin_amdgcn_readfirstlane(v);          // force wave-uniform
    const int b = ((wave >> 4) << 6) + lane;        // 64 consecutive b per wave

    float acc = b3[v];
    const float* __restrict__ W3v = W3 + v * (N_VAR * HID);

    for (int n = 0; n < N_VAR; ++n) {
        const int g = v * N_VAR + n;                // wave-uniform

        // ---- load x[b, g, 0..15] (64 B contiguous per lane) ----
        const float* __restrict__ xg = x + ((size_t)b * GRP + g) * LAGS;
        float xm[LAGS];
        #pragma unroll
        for (int l = 0; l < LAGS; l += 4) {
            const float4 t = *reinterpret_cast<const float4*>(xg + l);
            xm[l + 0] = t.x; xm[l + 1] = t.y; xm[l + 2] = t.z; xm[l + 3] = t.w;
        }

        // ---- mask (causal != 0), wave-uniform scalar loads ----
        const int* __restrict__ cg = causal + g * LAGS;
        #pragma unroll
        for (int l = 0; l < LAGS; ++l) {
            xm[l] = (cg[l] != 0) ? xm[l] : 0.0f;
        }

        // ---- conv1: h1[h] = sigmoid(b1 + sum_l xm[l] * W1[g,h,l]) ----
        const float* __restrict__ W1g = W1 + g * (HID * LAGS);
        const float* __restrict__ b1g = b1 + g * HID;
        float h1[HID];
        #pragma unroll
        for (int h = 0; h < HID; ++h) {
            float t = b1g[h];
            #pragma unroll
            for (int l = 0; l < LAGS; ++l)
                t += xm[l] * W1g[h * LAGS + l];
            h1[h] = sigmoid_fast(t);
        }

        // ---- conv2 + W3 partial: acc += sigmoid(b2 + W2 h1) . W3 ----
        const float* __restrict__ W2g = W2 + g * (HID * HID);
        const float* __restrict__ b2g = b2 + g * HID;
        #pragma unroll
        for (int k = 0; k < HID; ++k) {
            float t = b2g[k];
            #pragma unroll
            for (int h = 0; h < HID; ++h)
                t += h1[h] * W2g[k * HID + h];
            const float h2 = sigmoid_fast(t);
            acc += h2 * W3v[n * HID + k];
        }
    }

    out[(size_t)b * N_VAR + v] = acc;
}

extern "C" void kernel_launch(void* const* d_in, const int* in_sizes, int n_in,
                              void* d_out, int out_size, void* d_ws, size_t ws_size,
                              hipStream_t stream) {
    const float* x      = (const float*)d_in[0];
    const int*   causal = (const int*)  d_in[1];
    const float* W1     = (const float*)d_in[2];
    const float* b1     = (const float*)d_in[3];
    const float* W2     = (const float*)d_in[4];
    const float* b2     = (const float*)d_in[5];
    const float* W3     = (const float*)d_in[6];
    const float* b3     = (const float*)d_in[7];
    float* out          = (float*)d_out;

    // total threads = one per (b, v) pair = 32768 * 16 = 524288
    const int total   = BATCH * N_VAR;
    const int block   = 256;
    const int grid    = total / block;   // 2048 blocks
    additive_model_kernel<<<grid, block, 0, stream>>>(
        x, causal, W1, b1, W2, b2, W3, b3, out);
}

// Round 2
// 726.798 us; speedup vs baseline: 1.3567x; 1.3567x over previous
//
#include <hip/hip_runtime.h>
#include <hip/hip_bf16.h>

#define N_VAR 16
#define LAGS  16
#define HID   16
#define GRP   256        // N_VAR * N_VAR
#define BATCH 32768

typedef __attribute__((ext_vector_type(8))) short  bf16x8;
typedef __attribute__((ext_vector_type(4))) short  short4v;
typedef __attribute__((ext_vector_type(4))) float  floatx4;

__device__ __forceinline__ float sigmoid_fast(float t) {
    float e = __expf(-t);                      // v_mul + v_exp_f32
    return __builtin_amdgcn_rcpf(1.0f + e);    // v_add + v_rcp_f32
}

__device__ __forceinline__ short f2bf(float f) {
    __hip_bfloat16 h = __float2bfloat16(f);    // RNE
    return __builtin_bit_cast(short, h);
}

// ---------------------------------------------------------------------------
// Prologue: cast W1 (mask folded in) and W2 to bf16 in d_ws.
//   W1b[g][h][l] = bf16(W1[g][h][l] * (causal[g][l] != 0))
//   W2b[g][k][h] = bf16(W2[g][k][h])
// x*mask dot W1 == x dot (W1*mask), so the main kernel never touches causal.
// ---------------------------------------------------------------------------
__global__ __launch_bounds__(256) void prep_weights(
    const float* __restrict__ W1, const float* __restrict__ W2,
    const int* __restrict__ causal,
    short* __restrict__ W1b, short* __restrict__ W2b)
{
    const int i = blockIdx.x * 256 + threadIdx.x;   // 0 .. 65535 = G*H*L
    const int g = i >> 8;
    const int l = i & 15;
    const float msk = (causal[g * LAGS + l] != 0) ? 1.0f : 0.0f;
    W1b[i] = f2bf(W1[i] * msk);
    W2b[i] = f2bf(W2[i]);
}

// ---------------------------------------------------------------------------
// Main: one wave owns (variable v, 16 consecutive batch rows), loops n=0..15.
// K=32 mfma with interleaved zero-padding: frag slot j (j<4) of quad q holds
// real k = 4q+j; slots j>=4 are zero on both operands.
//   mfma1: D1[h][m]  = W1m[g] . xm^T + b1[g]     (A rows = h, B cols = m)
//   mfma2: D2[ko][m] = W2[g] . h1^T  + b2[g]
// D1's C/D fragment (row = 4q+r) IS mfma2's B fragment (k32=8q+j, j=r):
// no cross-lane exchange needed.
// ---------------------------------------------------------------------------
__global__ __launch_bounds__(256) void additive_mfma(
    const float* __restrict__ x,      // [B, G, L]
    const float* __restrict__ b1,     // [G, H]
    const float* __restrict__ b2,     // [G, H]
    const float* __restrict__ W3,     // [N, N*H]
    const float* __restrict__ b3,     // [N]
    const short* __restrict__ W1b,    // [G, H, L] bf16, masked
    const short* __restrict__ W2b,    // [G, H, H] bf16
    float* __restrict__ out)          // [B, N]
{
    const int lane = threadIdx.x & 63;
    const int w    = blockIdx.x * 4 + (threadIdx.x >> 6);
    const int v    = w & (N_VAR - 1);
    const int b0   = (w >> 4) * 16;          // 16 batch rows per wave
    const int m    = lane & 15;              // row index within fragments
    const int q    = lane >> 4;              // quad

    const float* __restrict__ xbase = x + (size_t)(b0 + m) * (GRP * LAGS) + q * 4;
    const float  b3v = b3[v];
    float acc = 0.0f;

    for (int n = 0; n < N_VAR; ++n) {
        const int g = v * N_VAR + n;

        // ---- B1 fragment: x[b0+m][g][4q .. 4q+3], slots 4..7 = 0 ----
        const floatx4 xv = *reinterpret_cast<const floatx4*>(xbase + g * LAGS);
        bf16x8 fx = {f2bf(xv[0]), f2bf(xv[1]), f2bf(xv[2]), f2bf(xv[3]),
                     (short)0, (short)0, (short)0, (short)0};

        // ---- A1 fragment: W1b[g][h=m][4q .. 4q+3] (8 B) ----
        const short4v w1v = *reinterpret_cast<const short4v*>(
            W1b + (g * HID + m) * LAGS + q * 4);
        bf16x8 fa1 = {w1v[0], w1v[1], w1v[2], w1v[3],
                      (short)0, (short)0, (short)0, (short)0};

        // ---- C1 = bias b1[g][row = 4q+r] ----
        floatx4 c1 = *reinterpret_cast<const floatx4*>(b1 + g * HID + q * 4);

        floatx4 d1 = __builtin_amdgcn_mfma_f32_16x16x32_bf16(fa1, fx, c1, 0, 0, 0);

        // ---- sigmoid -> B2 fragment (h1[m][h=4q+r] lives in reg r) ----
        bf16x8 fb2 = {f2bf(sigmoid_fast(d1[0])), f2bf(sigmoid_fast(d1[1])),
                      f2bf(sigmoid_fast(d1[2])), f2bf(sigmoid_fast(d1[3])),
                      (short)0, (short)0, (short)0, (short)0};

        // ---- A2 fragment: W2b[g][ko=m][4q .. 4q+3] ----
        const short4v w2v = *reinterpret_cast<const short4v*>(
            W2b + (g * HID + m) * HID + q * 4);
        bf16x8 fa2 = {w2v[0], w2v[1], w2v[2], w2v[3],
                      (short)0, (short)0, (short)0, (short)0};

        // ---- C2 = bias b2[g][row = 4q+r] ----
        floatx4 c2 = *reinterpret_cast<const floatx4*>(b2 + g * HID + q * 4);

        floatx4 d2 = __builtin_amdgcn_mfma_f32_16x16x32_bf16(fa2, fb2, c2, 0, 0, 0);

        // ---- epilogue partial: sum_r sigmoid(d2[r]) * W3[v][n*16 + 4q+r] ----
        const floatx4 w3v = *reinterpret_cast<const floatx4*>(
            W3 + v * (N_VAR * HID) + n * HID + q * 4);
        acc += sigmoid_fast(d2[0]) * w3v[0];
        acc += sigmoid_fast(d2[1]) * w3v[1];
        acc += sigmoid_fast(d2[2]) * w3v[2];
        acc += sigmoid_fast(d2[3]) * w3v[3];
    }

    // reduce over the 4 quads holding the same batch row m
    acc += __shfl_xor(acc, 16);
    acc += __shfl_xor(acc, 32);
    if (lane < 16)
        out[(size_t)(b0 + lane) * N_VAR + v] = acc + b3v;
}

extern "C" void kernel_launch(void* const* d_in, const int* in_sizes, int n_in,
                              void* d_out, int out_size, void* d_ws, size_t ws_size,
                              hipStream_t stream) {
    const float* x      = (const float*)d_in[0];
    const int*   causal = (const int*)  d_in[1];
    const float* W1     = (const float*)d_in[2];
    const float* b1     = (const float*)d_in[3];
    const float* W2     = (const float*)d_in[4];
    const float* b2     = (const float*)d_in[5];
    const float* W3     = (const float*)d_in[6];
    const float* b3     = (const float*)d_in[7];
    float* out          = (float*)d_out;

    short* W1b = (short*)d_ws;                        // 128 KB
    short* W2b = (short*)d_ws + GRP * HID * LAGS;     // next 128 KB

    prep_weights<<<(GRP * HID * LAGS) / 256, 256, 0, stream>>>(
        W1, W2, causal, W1b, W2b);

    const int n_waves  = (BATCH / 16) * N_VAR;        // 32768
    const int n_blocks = n_waves / 4;                 // 8192
    additive_mfma<<<n_blocks, 256, 0, stream>>>(
        x, b1, b2, W3, b3, W1b, W2b, out);
}